// Round 3
// baseline (360.049 us; speedup 1.0000x reference)
//
#include <hip/hip_runtime.h>
#include <math.h>

#define PN 22536
#define BN 32
#define MN 16
#define CN 81
#define NMB ((PN + 255) / 256)   // 89 match blocks per image (PN = 88*256 + 8)

// Native base-2 transcendentals (v_exp_f32 / v_log_f32) with safe fallback.
#if __has_builtin(__builtin_amdgcn_exp2f)
#define EXP2(x) __builtin_amdgcn_exp2f(x)
#else
#define EXP2(x) exp2f(x)
#endif
#if __has_builtin(__builtin_amdgcn_logf)
#define LOG2(x) __builtin_amdgcn_logf(x)
#else
#define LOG2(x) log2f(x)
#endif

// ---------------------------------------------------------------------------
// Kernel 1: per-object best-prior argmax (prior_for_each_object).
// f32 max-reduce + ballot elects the wave winner (first lane = smallest p);
// cross-wave/block combine keeps the exact packed u64 key (iou_bits<<32 | ~p).
// ---------------------------------------------------------------------------
__global__ __launch_bounds__(256)
void pfo_kernel(const float* __restrict__ boxes,    // (B,M,4) xyxy
                const float* __restrict__ priors,   // (P,4) cxcy
                unsigned long long* __restrict__ pfo_key) // (B,M)
{
    const int b = blockIdx.y;
    const int p = blockIdx.x * 256 + threadIdx.x;

    __shared__ float4 sbox[MN];
    __shared__ float  sarea[MN];
    __shared__ unsigned long long skey[MN];
    if (threadIdx.x < MN) {
        float4 bx = reinterpret_cast<const float4*>(boxes)[b * MN + threadIdx.x];
        sbox[threadIdx.x]  = bx;
        sarea[threadIdx.x] = (bx.z - bx.x) * (bx.w - bx.y);
        skey[threadIdx.x]  = 0ull;
    }
    __syncthreads();

    float x0 = 0.f, y0 = 0.f, x1 = 0.f, y1 = 0.f, ab = 0.f;
    const bool valid = (p < PN);
    if (valid) {
        float4 pc = reinterpret_cast<const float4*>(priors)[p];
        float hw = pc.z / 2.0f, hh = pc.w / 2.0f;
        x0 = pc.x - hw; y0 = pc.y - hh;
        x1 = pc.x + hw; y1 = pc.y + hh;
        ab = (x1 - x0) * (y1 - y0);
    }

    const int lane = threadIdx.x & 63;
    #pragma unroll
    for (int m = 0; m < MN; ++m) {
        float iou = -INFINITY;
        if (valid) {
            float4 bx = sbox[m];
            float lx = fmaxf(bx.x, x0), ly = fmaxf(bx.y, y0);
            float rx = fminf(bx.z, x1), ry = fminf(bx.w, y1);
            float inter = fmaxf(rx - lx, 0.0f) * fmaxf(ry - ly, 0.0f);
            iou = inter / (sarea[m] + ab - inter);      // >= 0 for valid lanes
        }
        float mx = iou;
        #pragma unroll
        for (int off = 1; off < 64; off <<= 1)
            mx = fmaxf(mx, __shfl_xor(mx, off, 64));
        unsigned long long mask = __ballot(iou == mx);
        int lane0 = (int)__ffsll((unsigned long long)mask) - 1;
        if (valid && lane == lane0) {
            unsigned long long key =
                ((unsigned long long)__float_as_uint(iou) << 32) |
                (unsigned long long)(~(unsigned int)p);
            atomicMax(&skey[m], key);
        }
    }
    __syncthreads();
    if (threadIdx.x < MN)
        atomicMax(&pfo_key[b * MN + threadIdx.x], skey[threadIdx.x]);
}

// ---------------------------------------------------------------------------
// Kernel 2 (fused match + focal conf):
// Phase A: thread-per-prior matching + DIoU; label byte kept in LDS.
// Phase B: focal loss, 8-row packs/wave, double-buffered LDS + 2-deep
//   software pipeline: compute(it) from buf[it&1] overlaps ds_write of
//   it+1 into buf[(it+1)&1] and global float4 loads of it+2 (T14/G15).
// Emits per-block float4 (loc_sum, pos_cnt, m_cnt, conf_sum).
// ---------------------------------------------------------------------------
__global__ __launch_bounds__(256)
void match_conf_kernel(const float* __restrict__ boxes,   // (B,M,4)
                       const int*   __restrict__ labels,  // (B,M)
                       const float* __restrict__ priors,  // (P,4) cxcy
                       const float* __restrict__ plocs,   // (B,P,4)
                       const float* __restrict__ scores,  // (B,P,C)
                       const unsigned long long* __restrict__ pfo_key,
                       float4* __restrict__ mpart)        // (B*NMB)
{
    const int b  = blockIdx.y;
    const int p0 = blockIdx.x * 256;
    const int p  = p0 + threadIdx.x;

    __shared__ float4 sbox[MN];
    __shared__ float  sarea[MN];
    __shared__ int    slab[MN];
    __shared__ int    spfo[MN];
    __shared__ unsigned char slb[256];
    __shared__ float4 spack4[4][2][162];  // per-wave double-buffered 8-row pack
    __shared__ float  sred[4][4];

    if (threadIdx.x < MN) {
        float4 bx = reinterpret_cast<const float4*>(boxes)[b * MN + threadIdx.x];
        sbox[threadIdx.x]  = bx;
        sarea[threadIdx.x] = (bx.z - bx.x) * (bx.w - bx.y);
        slab[threadIdx.x]  = labels[b * MN + threadIdx.x];
        spfo[threadIdx.x]  = (int)(~(unsigned int)(pfo_key[b * MN + threadIdx.x] &
                                                   0xFFFFFFFFull));
    }
    __syncthreads();

    // ---------------- phase A: matching ----------------
    float loc = 0.f, mc = 0.f, psc = 0.f;
    unsigned char myl = 255;
    if (p < PN) {
        float4 pc = reinterpret_cast<const float4*>(priors)[p];
        float hw = pc.z / 2.0f, hh = pc.w / 2.0f;
        float qx0 = pc.x - hw, qy0 = pc.y - hh;
        float qx1 = pc.x + hw, qy1 = pc.y + hh;
        float ab  = (qx1 - qx0) * (qy1 - qy0);

        float best = -1.0f;
        int bestm = 0;
        #pragma unroll
        for (int m = 0; m < MN; ++m) {
            float4 bx = sbox[m];
            float lx = fmaxf(bx.x, qx0), ly = fmaxf(bx.y, qy0);
            float rx = fminf(bx.z, qx1), ry = fminf(bx.w, qy1);
            float inter = fmaxf(rx - lx, 0.0f) * fmaxf(ry - ly, 0.0f);
            float iou = inter / (sarea[m] + ab - inter);
            if (iou > best) { best = iou; bestm = m; }   // first-index wins
        }
        // pfo override: ascending m => last m wins for duplicate priors
        #pragma unroll
        for (int m = 0; m < MN; ++m)
            if (spfo[m] == p) { bestm = m; best = 1.0f; }

        bool pos = best >= 0.5f;
        bool neg = best < 0.4f;
        myl = pos ? (unsigned char)slab[bestm]
                  : (neg ? (unsigned char)0 : (unsigned char)255);
        if (pos || neg) mc = 1.0f;

        if (pos) {
            float4 g = reinterpret_cast<const float4*>(plocs)[(size_t)b * PN + p];
            float cx = g.x * pc.z / 10.0f + pc.x;
            float cy = g.y * pc.w / 10.0f + pc.y;
            float ww = expf(g.z / 5.0f) * pc.z;
            float hh2 = expf(g.w / 5.0f) * pc.w;
            float px0 = cx - ww / 2.0f, py0 = cy - hh2 / 2.0f;
            float px1 = cx + ww / 2.0f, py1 = cy + hh2 / 2.0f;

            float4 gb = sbox[bestm];
            float lx = fmaxf(px0, gb.x), ly = fmaxf(py0, gb.y);
            float rx = fminf(px1, gb.z), ry = fminf(py1, gb.w);
            float inter = fmaxf(rx - lx, 0.f) * fmaxf(ry - ly, 0.f);
            float apx = (px1 - px0) * (py1 - py0);
            float agx = (gb.z - gb.x) * (gb.w - gb.y);
            float iou = inter / (apx + agx - inter + 1e-7f);
            float cpx = (px0 + px1) / 2.0f, cpy = (py0 + py1) / 2.0f;
            float cgx = (gb.x + gb.z) / 2.0f, cgy = (gb.y + gb.w) / 2.0f;
            float dx = cpx - cgx, dy = cpy - cgy;
            float d2 = dx * dx + dy * dy;
            float ex0 = fminf(px0, gb.x), ey0 = fminf(py0, gb.y);
            float ex1 = fmaxf(px1, gb.z), ey1 = fmaxf(py1, gb.w);
            float ew = ex1 - ex0, eh = ey1 - ey0;
            float c2 = ew * ew + eh * eh + 1e-7f;
            loc = 1.0f - iou + d2 / c2;
            psc = 1.0f;
        }
    }
    slb[threadIdx.x] = myl;

    #pragma unroll
    for (int off = 32; off >= 1; off >>= 1) {
        loc += __shfl_down(loc, (unsigned)off, 64);
        mc  += __shfl_down(mc,  (unsigned)off, 64);
        psc += __shfl_down(psc, (unsigned)off, 64);
    }
    const int lane = threadIdx.x & 63;
    const int w    = threadIdx.x >> 6;
    if (lane == 0) { sred[w][0] = loc; sred[w][1] = mc; sred[w][2] = psc; }
    __syncthreads();   // slb + sred visible to all waves

    // ---------------- phase B: focal conf (2-deep pipeline) ----------------
    const int g8 = lane >> 3;          // row within pack (0..7)
    const int j  = lane & 7;           // 8 lanes per row
    const bool v34 = (lane < 34);
    const float LOG2E = 1.4426950408889634f;
    const float LN2   = 0.6931471805599453f;

    float confs = 0.f;
    float4 r0 = make_float4(0, 0, 0, 0), r1 = r0, r2 = r0;

    // valid(it): pack start prior index in range (PN%8==0 -> pack fully valid)
    #define PKVALID(it) ((p0 + w * 64 + (it) * 8) < PN)
    #define PKADDR(it) (reinterpret_cast<const float4*>(                    \
        scores + ((size_t)b * PN + (p0 + w * 64 + (it) * 8)) * (size_t)CN))

    // prologue: load it=0, stage it=0 into buf0, load it=1
    if (PKVALID(0)) {
        const float4* gsrc = PKADDR(0);
        r0 = gsrc[lane]; r1 = gsrc[lane + 64];
        if (v34) r2 = gsrc[lane + 128];
        float4* d = spack4[w][0];
        d[lane] = r0; d[lane + 64] = r1;
        if (v34) d[lane + 128] = r2;
    }
    if (PKVALID(1)) {
        const float4* gsrc = PKADDR(1);
        r0 = gsrc[lane]; r1 = gsrc[lane + 64];
        if (v34) r2 = gsrc[lane + 128];
    }

    #pragma unroll
    for (int it = 0; it < 8; ++it) {
        // stage it+1 into the other buffer (r holds it+1's data)
        if (it + 1 < 8 && PKVALID(it + 1)) {
            float4* d = spack4[w][(it + 1) & 1];
            d[lane] = r0; d[lane + 64] = r1;
            if (v34) d[lane + 128] = r2;
        }
        // issue global loads for it+2 (latency hidden under compute below)
        if (it + 2 < 8 && PKVALID(it + 2)) {
            const float4* gsrc = PKADDR(it + 2);
            r0 = gsrc[lane]; r1 = gsrc[lane + 64];
            if (v34) r2 = gsrc[lane + 128];
        }
        // compute it from buf[it&1]
        if (PKVALID(it)) {
            const int prow = w * 64 + it * 8;
            const float* rowp =
                reinterpret_cast<const float*>(spack4[w][it & 1]) + g8 * 81;

            float v[10];
            #pragma unroll
            for (int k = 0; k < 10; ++k) v[k] = rowp[j + 8 * k];
            float v80 = (j == 0) ? rowp[80] : -INFINITY;

            float mx = v80;
            #pragma unroll
            for (int k = 0; k < 10; ++k) mx = fmaxf(mx, v[k]);
            #pragma unroll
            for (int off = 1; off < 8; off <<= 1)
                mx = fmaxf(mx, __shfl_xor(mx, off, 64));

            const float mx2 = mx * LOG2E;
            float es = EXP2(fmaf(v80, LOG2E, -mx2));   // exp2(-inf)=0 for j!=0
            #pragma unroll
            for (int k = 0; k < 10; ++k)
                es += EXP2(fmaf(v[k], LOG2E, -mx2));
            #pragma unroll
            for (int off = 1; off < 8; off <<= 1)
                es += __shfl_xor(es, off, 64);

            const int lb  = slb[prow + g8];
            const int lbe = (lb == 255) ? 0 : lb;
            const float st = rowp[lbe];                // group-uniform broadcast
            float q  = fmaf(st, LOG2E, -mx2) - LOG2(es);  // log2 p_t
            float pt = EXP2(q);
            float om = 1.0f - pt;
            float fl = 0.25f * om * om * (-(q * LN2));
            if (j == 0 && lb != 255) confs += fl;
        }
    }
    #undef PKVALID
    #undef PKADDR

    #pragma unroll
    for (int off = 1; off < 64; off <<= 1)
        confs += __shfl_xor(confs, off, 64);
    if (lane == 0) sred[w][3] = confs;
    __syncthreads();

    if (threadIdx.x == 0) {
        float a = 0.f, bsum = 0.f, c = 0.f, cf = 0.f;
        #pragma unroll
        for (int i = 0; i < 4; ++i) {
            a += sred[i][0]; bsum += sred[i][1]; c += sred[i][2]; cf += sred[i][3];
        }
        mpart[b * NMB + blockIdx.x] = make_float4(a, c, bsum, cf);
    }
}

// ---------------------------------------------------------------------------
// Kernel 3: deterministic final reduction -> scalar loss
// ---------------------------------------------------------------------------
__global__ __launch_bounds__(256)
void reduce_kernel(const float4* __restrict__ mpart,   // (B*NMB): loc,pos,mcnt,conf
                   float* __restrict__ out)
{
    const int NM = BN * NMB;
    float loc = 0.f, pcnt = 0.f, mcnt = 0.f, conf = 0.f;
    for (int i = threadIdx.x; i < NM; i += 256) {
        float4 v = mpart[i];
        loc += v.x; pcnt += v.y; mcnt += v.z; conf += v.w;
    }

    #pragma unroll
    for (int off = 1; off < 64; off <<= 1) {
        loc  += __shfl_xor(loc,  off, 64);
        pcnt += __shfl_xor(pcnt, off, 64);
        mcnt += __shfl_xor(mcnt, off, 64);
        conf += __shfl_xor(conf, off, 64);
    }
    __shared__ float s[4][4];
    int lane = threadIdx.x & 63, w = threadIdx.x >> 6;
    if (lane == 0) { s[w][0] = loc; s[w][1] = pcnt; s[w][2] = mcnt; s[w][3] = conf; }
    __syncthreads();
    if (threadIdx.x == 0) {
        float L = 0.f, Pc = 0.f, Mc = 0.f, Cf = 0.f;
        #pragma unroll
        for (int i = 0; i < 4; ++i) {
            L += s[i][0]; Pc += s[i][1]; Mc += s[i][2]; Cf += s[i][3];
        }
        out[0] = Cf / fmaxf(Mc, 1.0f) + L / fmaxf(Pc, 1.0f);
    }
}

// ---------------------------------------------------------------------------
extern "C" void kernel_launch(void* const* d_in, const int* in_sizes, int n_in,
                              void* d_out, int out_size, void* d_ws, size_t ws_size,
                              hipStream_t stream)
{
    const float* plocs  = (const float*)d_in[0];  // predicted_locs  (B,P,4)
    const float* scores = (const float*)d_in[1];  // predicted_scores(B,P,C)
    const float* boxes  = (const float*)d_in[2];  // boxes           (B,M,4)
    const int*   labels = (const int*)d_in[3];    // labels          (B,M)
    const float* priors = (const float*)d_in[4];  // priors_cxcy     (P,4)
    float* out = (float*)d_out;

    char* ws = (char*)d_ws;
    unsigned long long* pfo_key = (unsigned long long*)ws;   // 4096 B
    float4* mpart = (float4*)(ws + 4096);                    // 2848*16 B

    hipMemsetAsync(pfo_key, 0, BN * MN * sizeof(unsigned long long), stream);

    dim3 gA(NMB, BN);
    pfo_kernel<<<gA, 256, 0, stream>>>(boxes, priors, pfo_key);
    match_conf_kernel<<<gA, 256, 0, stream>>>(boxes, labels, priors, plocs,
                                              scores, pfo_key, mpart);
    reduce_kernel<<<1, 256, 0, stream>>>(mpart, out);
}